// Round 1
// baseline (1661.750 us; speedup 1.0000x reference)
//
#include <hip/hip_runtime.h>
#include <cstdint>
#include <cstddef>

#define B_ 2048
#define N_ 256

typedef unsigned short u16;
typedef __attribute__((ext_vector_type(8))) short short8;
typedef __attribute__((ext_vector_type(4))) float floatx4;

__device__ __forceinline__ u16 f2bf(float f) {
  union { float f; unsigned u; } v; v.f = f;
  unsigned u = v.u;
  return (u16)((u + 0x7FFFu + ((u >> 16) & 1u)) >> 16);
}
__device__ __forceinline__ float tanh_fast(float x) {
  x = fmaxf(fminf(x, 30.0f), -30.0f);
  float u = __expf(-2.0f * x);
  return __fdividef(1.0f - u, 1.0f + u);
}

// ---------------- prep: pack weight matrix W[K][Ncols] (fp32, row-major) into
// MFMA-fragment-ordered bf16 blob: elem index = ((nt*ksteps + ks)*64 + lane)*8 + j
// lane -> col = nt*16 + (lane&15), k = ks*32 + (lane>>4)*8 + j
__global__ void rlp_pack_frag(const float* __restrict__ W, u16* __restrict__ dst,
                              int K, int Ncols, int ksteps, int ntiles) {
  int e = blockIdx.x * blockDim.x + threadIdx.x;
  int total = ntiles * ksteps * 512;
  if (e >= total) return;
  int j = e & 7;
  int lane = (e >> 3) & 63;
  int tt = e >> 9;               // nt*ksteps + ks
  int ks = tt % ksteps;
  int nt = tt / ksteps;
  int col = nt * 16 + (lane & 15);
  int k = ks * 32 + ((lane >> 4) << 3) + j;
  float v = 0.0f;
  if (k < K && col < Ncols) v = W[k * Ncols + col];
  dst[e] = f2bf(v);
}

// ctx_emb = tanh(context @ ce_w + ce_b)   [B,64], stored bf16 (for x assembly) + fp32 (for z0)
__global__ void rlp_ctx_kernel(const float* __restrict__ ctx, const float* __restrict__ cew,
                               const float* __restrict__ ceb,
                               u16* __restrict__ ctxb, float* __restrict__ ctxf) {
  int i = blockIdx.x * blockDim.x + threadIdx.x;
  if (i >= B_ * 64) return;
  int b = i >> 6, c = i & 63;
  float s = ceb[c];
#pragma unroll
  for (int k = 0; k < 32; k++) s += ctx[b * 32 + k] * cew[k * 64 + c];
  float v = tanhf(s);
  ctxf[i] = v;
  ctxb[i] = f2bf(v);
}

// z0 = tanh(ctx_emb @ z0_w + z0_b)   [B,64] fp32
__global__ void rlp_z0_kernel(const float* __restrict__ ctxf, const float* __restrict__ z0w,
                              const float* __restrict__ z0b, float* __restrict__ z0f) {
  int i = blockIdx.x * blockDim.x + threadIdx.x;
  if (i >= B_ * 64) return;
  int b = i >> 6, l = i & 63;
  float s = z0b[l];
  for (int c = 0; c < 64; c++) s += ctxf[b * 64 + c] * z0w[c * 64 + l];
  z0f[i] = tanhf(s);
}

// ---------------- LayerNorm(+tanh) applied to two 16-col accumulator tiles, result -> hout (bf16)
// M = number of active batch rows (8 for scan, 16 for decoder). cols = 128 always.
template <int M>
__device__ __forceinline__ void ln_tanh_store(
    floatx4 a0, floatx4 a1,
    const float* __restrict__ g, const float* __restrict__ be,
    u16 (*hout)[136], int wave, int lane,
    float (*lnpart)[16][2], float (*lnmr)[2]) {
  int rbase = (lane >> 4) * 4;
  float s[4], q[4];
#pragma unroll
  for (int r = 0; r < 4; r++) {
    s[r] = a0[r] + a1[r];
    q[r] = a0[r] * a0[r] + a1[r] * a1[r];
  }
#pragma unroll
  for (int off = 1; off <= 8; off <<= 1) {
#pragma unroll
    for (int r = 0; r < 4; r++) {
      s[r] += __shfl_xor(s[r], off, 64);
      q[r] += __shfl_xor(q[r], off, 64);
    }
  }
  if ((lane & 15) == 0 && rbase < M) {
#pragma unroll
    for (int r = 0; r < 4; r++) {
      lnpart[wave][rbase + r][0] = s[r];
      lnpart[wave][rbase + r][1] = q[r];
    }
  }
  __syncthreads();
  if (threadIdx.x < M) {
    float S = 0.0f, Q = 0.0f;
#pragma unroll
    for (int w = 0; w < 4; w++) { S += lnpart[w][threadIdx.x][0]; Q += lnpart[w][threadIdx.x][1]; }
    float mean = S * (1.0f / 128.0f);
    float var = Q * (1.0f / 128.0f) - mean * mean;
    lnmr[threadIdx.x][0] = mean;
    lnmr[threadIdx.x][1] = rsqrtf(var + 1e-5f);
  }
  __syncthreads();
  if (rbase < M) {
    int col0 = (wave * 2 + 0) * 16 + (lane & 15);
    int col1 = (wave * 2 + 1) * 16 + (lane & 15);
    float gg0 = g[col0], bb0 = be[col0];
    float gg1 = g[col1], bb1 = be[col1];
#pragma unroll
    for (int r = 0; r < 4; r++) {
      int row = rbase + r;
      float m = lnmr[row][0], rs = lnmr[row][1];
      float v0 = (a0[r] - m) * rs * gg0 + bb0;
      float v1 = (a1[r] - m) * rs * gg1 + bb1;
      hout[row][col0] = f2bf(tanh_fast(v0));
      hout[row][col1] = f2bf(tanh_fast(v1));
    }
  }
  __syncthreads();
}

// ---------------- scan: 8 batch rows per WG, 255 sequential steps, dynamics MLP via MFMA.
// Dyn frag blob offsets (elems): L1@0 (K160,ks5,nt8)=20480; L2@20480 (ks4,nt8)=16384;
// L3@36864; L4@53248 (ks4,nt4)=8192. Total 61440.
__global__ __launch_bounds__(256, 1) void rlp_scan_kernel(
    const float* __restrict__ t,
    const u16* __restrict__ wblob,
    const u16* __restrict__ ctxb,
    const float* __restrict__ z0f,
    const float* __restrict__ db0, const float* __restrict__ db1,
    const float* __restrict__ db2, const float* __restrict__ db3,
    const float* __restrict__ dg0, const float* __restrict__ dbe0,
    const float* __restrict__ dg1, const float* __restrict__ dbe1,
    const float* __restrict__ dg2, const float* __restrict__ dbe2,
    u16* __restrict__ ztraj, int b0) {
  __shared__ __align__(16) u16 wf[61440];
  __shared__ __align__(16) u16 xb[16][160];   // [z(64) | t_emb(17) | ctx(64) | pad0]
  __shared__ __align__(16) u16 hA[16][136];
  __shared__ __align__(16) u16 hB[16][136];
  __shared__ float zst[8][64];
  __shared__ float bias1[128], bias2[128], bias3[128], bias4[64];
  __shared__ float g1[128], be1[128], g2[128], be2[128], g3[128], be3[128];
  __shared__ float dts[8];
  __shared__ float lnpart[4][16][2];
  __shared__ float lnmr[16][2];

  const int tid = threadIdx.x;
  const int wave = tid >> 6;
  const int lane = tid & 63;
  const int rowblk = blockIdx.x;
  const int gb = b0 + rowblk * 8;

  // stage weights (fragment-ordered bf16) into LDS
  {
    const float4* src = reinterpret_cast<const float4*>(wblob);
    float4* dst = reinterpret_cast<float4*>(wf);
    for (int i = tid; i < 61440 / 8; i += 256) dst[i] = src[i];
  }
  for (int i = tid; i < 128; i += 256) {
    bias1[i] = db0[i]; bias2[i] = db1[i]; bias3[i] = db2[i];
    g1[i] = dg0[i]; be1[i] = dbe0[i];
    g2[i] = dg1[i]; be2[i] = dbe1[i];
    g3[i] = dg2[i]; be3[i] = dbe2[i];
  }
  if (tid < 64) bias4[tid] = db3[tid];
  for (int i = tid; i < 16 * 160; i += 256) (&xb[0][0])[i] = 0;
  for (int i = tid; i < 16 * 136; i += 256) { (&hA[0][0])[i] = 0; (&hB[0][0])[i] = 0; }
  __syncthreads();
  // ctx_emb + z0 into xb / zst; z_traj[:,0] = z0
  for (int i = tid; i < 8 * 64; i += 256) {
    int r = i >> 6, c = i & 63;
    xb[r][81 + c] = ctxb[(gb + r) * 64 + c];
    float z = z0f[(gb + r) * 64 + c];
    zst[r][c] = z;
    u16 zb = f2bf(z);
    xb[r][c] = zb;
    ztraj[((size_t)(rowblk * 8 + r) * 256 + 0) * 64 + c] = zb;
  }
  __syncthreads();

  const int arow = lane & 15;
  const int agrp = lane >> 4;
  const int acol = lane & 15;
  const int rbase = agrp * 4;

  for (int n = 0; n < N_ - 1; n++) {
    // t_emb + dt
    if (tid < 8) {
      float t0 = t[(gb + tid) * N_ + n];
      float t1 = t[(gb + tid) * N_ + n + 1];
      dts[tid] = t1 - t0;
    }
    if (tid < 136) {
      int r = tid / 17, j = tid - r * 17;
      float tv = t[(gb + r) * N_ + n];
      float val;
      if (j == 0) val = tv;
      else if (j <= 8) val = __sinf(tv * (3.14159265358979f * (float)(1 << (j - 1))));
      else val = __cosf(tv * (3.14159265358979f * (float)(1 << (j - 9))));
      xb[r][64 + j] = f2bf(val);
    }
    __syncthreads();

    // L1: xb (K=160, 5 ksteps) -> hA
    {
      float bc0 = bias1[(wave * 2 + 0) * 16 + acol];
      float bc1 = bias1[(wave * 2 + 1) * 16 + acol];
      floatx4 acc0 = {bc0, bc0, bc0, bc0};
      floatx4 acc1 = {bc1, bc1, bc1, bc1};
#pragma unroll
      for (int ks = 0; ks < 5; ks++) {
        short8 a = *reinterpret_cast<const short8*>(&xb[arow][ks * 32 + agrp * 8]);
        short8 bv0 = *reinterpret_cast<const short8*>(&wf[(((wave * 2 + 0) * 5 + ks) * 64 + lane) * 8]);
        short8 bv1 = *reinterpret_cast<const short8*>(&wf[(((wave * 2 + 1) * 5 + ks) * 64 + lane) * 8]);
        acc0 = __builtin_amdgcn_mfma_f32_16x16x32_bf16(a, bv0, acc0, 0, 0, 0);
        acc1 = __builtin_amdgcn_mfma_f32_16x16x32_bf16(a, bv1, acc1, 0, 0, 0);
      }
      ln_tanh_store<8>(acc0, acc1, g1, be1, hA, wave, lane, lnpart, lnmr);
    }
    // L2: hA -> hB
    {
      float bc0 = bias2[(wave * 2 + 0) * 16 + acol];
      float bc1 = bias2[(wave * 2 + 1) * 16 + acol];
      floatx4 acc0 = {bc0, bc0, bc0, bc0};
      floatx4 acc1 = {bc1, bc1, bc1, bc1};
#pragma unroll
      for (int ks = 0; ks < 4; ks++) {
        short8 a = *reinterpret_cast<const short8*>(&hA[arow][ks * 32 + agrp * 8]);
        short8 bv0 = *reinterpret_cast<const short8*>(&wf[20480 + (((wave * 2 + 0) * 4 + ks) * 64 + lane) * 8]);
        short8 bv1 = *reinterpret_cast<const short8*>(&wf[20480 + (((wave * 2 + 1) * 4 + ks) * 64 + lane) * 8]);
        acc0 = __builtin_amdgcn_mfma_f32_16x16x32_bf16(a, bv0, acc0, 0, 0, 0);
        acc1 = __builtin_amdgcn_mfma_f32_16x16x32_bf16(a, bv1, acc1, 0, 0, 0);
      }
      ln_tanh_store<8>(acc0, acc1, g2, be2, hB, wave, lane, lnpart, lnmr);
    }
    // L3: hB -> hA
    {
      float bc0 = bias3[(wave * 2 + 0) * 16 + acol];
      float bc1 = bias3[(wave * 2 + 1) * 16 + acol];
      floatx4 acc0 = {bc0, bc0, bc0, bc0};
      floatx4 acc1 = {bc1, bc1, bc1, bc1};
#pragma unroll
      for (int ks = 0; ks < 4; ks++) {
        short8 a = *reinterpret_cast<const short8*>(&hB[arow][ks * 32 + agrp * 8]);
        short8 bv0 = *reinterpret_cast<const short8*>(&wf[36864 + (((wave * 2 + 0) * 4 + ks) * 64 + lane) * 8]);
        short8 bv1 = *reinterpret_cast<const short8*>(&wf[36864 + (((wave * 2 + 1) * 4 + ks) * 64 + lane) * 8]);
        acc0 = __builtin_amdgcn_mfma_f32_16x16x32_bf16(a, bv0, acc0, 0, 0, 0);
        acc1 = __builtin_amdgcn_mfma_f32_16x16x32_bf16(a, bv1, acc1, 0, 0, 0);
      }
      ln_tanh_store<8>(acc0, acc1, g3, be3, hA, wave, lane, lnpart, lnmr);
    }
    // L4: hA -> dz (64 cols, nt = wave), z update
    {
      float bc = bias4[wave * 16 + acol];
      floatx4 acc = {bc, bc, bc, bc};
#pragma unroll
      for (int ks = 0; ks < 4; ks++) {
        short8 a = *reinterpret_cast<const short8*>(&hA[arow][ks * 32 + agrp * 8]);
        short8 bv = *reinterpret_cast<const short8*>(&wf[53248 + ((wave * 4 + ks) * 64 + lane) * 8]);
        acc = __builtin_amdgcn_mfma_f32_16x16x32_bf16(a, bv, acc, 0, 0, 0);
      }
      if (rbase < 8) {
        int col = wave * 16 + acol;
#pragma unroll
        for (int r = 0; r < 4; r++) {
          int row = rbase + r;
          float z = zst[row][col] + dts[row] * acc[r];
          zst[row][col] = z;
          u16 zb = f2bf(z);
          xb[row][col] = zb;
          ztraj[((size_t)(rowblk * 8 + row) * 256 + (n + 1)) * 64 + col] = zb;
        }
      }
    }
    __syncthreads();
  }
}

// ---------------- decoder: persistent, 16 rows per iter.
// Dec blob offsets: L1@0 (K64,ks2,nt8)=8192; L2@8192; L3@24576; L4@40960 (ks4,nt1)=2048.
__global__ __launch_bounds__(256, 1) void rlp_dec_kernel(
    const u16* __restrict__ wblob,
    const u16* __restrict__ ztraj,
    const float* __restrict__ eb0, const float* __restrict__ eb1,
    const float* __restrict__ eb2, const float* __restrict__ eb3,
    const float* __restrict__ eg0, const float* __restrict__ ebe0,
    const float* __restrict__ eg1, const float* __restrict__ ebe1,
    const float* __restrict__ eg2, const float* __restrict__ ebe2,
    float* __restrict__ out, int b0, int nrows) {
  __shared__ __align__(16) u16 wf[43008];
  __shared__ __align__(16) u16 xz[16][72];
  __shared__ __align__(16) u16 hA[16][136];
  __shared__ __align__(16) u16 hB[16][136];
  __shared__ float bias1[128], bias2[128], bias3[128], bias4[16];
  __shared__ float g1[128], be1[128], g2[128], be2[128], g3[128], be3[128];
  __shared__ float lnpart[4][16][2];
  __shared__ float lnmr[16][2];

  const int tid = threadIdx.x;
  const int wave = tid >> 6;
  const int lane = tid & 63;

  {
    const float4* src = reinterpret_cast<const float4*>(wblob);
    float4* dst = reinterpret_cast<float4*>(wf);
    for (int i = tid; i < 43008 / 8; i += 256) dst[i] = src[i];
  }
  for (int i = tid; i < 128; i += 256) {
    bias1[i] = eb0[i]; bias2[i] = eb1[i]; bias3[i] = eb2[i];
    g1[i] = eg0[i]; be1[i] = ebe0[i];
    g2[i] = eg1[i]; be2[i] = ebe1[i];
    g3[i] = eg2[i]; be3[i] = ebe2[i];
  }
  if (tid < 16) bias4[tid] = (tid < 14) ? eb3[tid] : 0.0f;
  __syncthreads();

  const int arow = lane & 15;
  const int agrp = lane >> 4;
  const int acol = lane & 15;
  const int rbase = agrp * 4;

  const int ntile_total = nrows / 16;
  for (int tile = blockIdx.x; tile < ntile_total; tile += gridDim.x) {
    const int row0 = tile * 16;
    if (tid < 128) {
      int r = tid >> 3, p = tid & 7;
      *reinterpret_cast<uint4*>(&xz[r][p * 8]) =
          *reinterpret_cast<const uint4*>(&ztraj[(size_t)(row0 + r) * 64 + p * 8]);
    }
    __syncthreads();
    // L1: xz (K=64, 2 ksteps) -> hA
    {
      float bc0 = bias1[(wave * 2 + 0) * 16 + acol];
      float bc1 = bias1[(wave * 2 + 1) * 16 + acol];
      floatx4 acc0 = {bc0, bc0, bc0, bc0};
      floatx4 acc1 = {bc1, bc1, bc1, bc1};
#pragma unroll
      for (int ks = 0; ks < 2; ks++) {
        short8 a = *reinterpret_cast<const short8*>(&xz[arow][ks * 32 + agrp * 8]);
        short8 bv0 = *reinterpret_cast<const short8*>(&wf[(((wave * 2 + 0) * 2 + ks) * 64 + lane) * 8]);
        short8 bv1 = *reinterpret_cast<const short8*>(&wf[(((wave * 2 + 1) * 2 + ks) * 64 + lane) * 8]);
        acc0 = __builtin_amdgcn_mfma_f32_16x16x32_bf16(a, bv0, acc0, 0, 0, 0);
        acc1 = __builtin_amdgcn_mfma_f32_16x16x32_bf16(a, bv1, acc1, 0, 0, 0);
      }
      ln_tanh_store<16>(acc0, acc1, g1, be1, hA, wave, lane, lnpart, lnmr);
    }
    // L2: hA -> hB
    {
      float bc0 = bias2[(wave * 2 + 0) * 16 + acol];
      float bc1 = bias2[(wave * 2 + 1) * 16 + acol];
      floatx4 acc0 = {bc0, bc0, bc0, bc0};
      floatx4 acc1 = {bc1, bc1, bc1, bc1};
#pragma unroll
      for (int ks = 0; ks < 4; ks++) {
        short8 a = *reinterpret_cast<const short8*>(&hA[arow][ks * 32 + agrp * 8]);
        short8 bv0 = *reinterpret_cast<const short8*>(&wf[8192 + (((wave * 2 + 0) * 4 + ks) * 64 + lane) * 8]);
        short8 bv1 = *reinterpret_cast<const short8*>(&wf[8192 + (((wave * 2 + 1) * 4 + ks) * 64 + lane) * 8]);
        acc0 = __builtin_amdgcn_mfma_f32_16x16x32_bf16(a, bv0, acc0, 0, 0, 0);
        acc1 = __builtin_amdgcn_mfma_f32_16x16x32_bf16(a, bv1, acc1, 0, 0, 0);
      }
      ln_tanh_store<16>(acc0, acc1, g2, be2, hB, wave, lane, lnpart, lnmr);
    }
    // L3: hB -> hA
    {
      float bc0 = bias3[(wave * 2 + 0) * 16 + acol];
      float bc1 = bias3[(wave * 2 + 1) * 16 + acol];
      floatx4 acc0 = {bc0, bc0, bc0, bc0};
      floatx4 acc1 = {bc1, bc1, bc1, bc1};
#pragma unroll
      for (int ks = 0; ks < 4; ks++) {
        short8 a = *reinterpret_cast<const short8*>(&hB[arow][ks * 32 + agrp * 8]);
        short8 bv0 = *reinterpret_cast<const short8*>(&wf[24576 + (((wave * 2 + 0) * 4 + ks) * 64 + lane) * 8]);
        short8 bv1 = *reinterpret_cast<const short8*>(&wf[24576 + (((wave * 2 + 1) * 4 + ks) * 64 + lane) * 8]);
        acc0 = __builtin_amdgcn_mfma_f32_16x16x32_bf16(a, bv0, acc0, 0, 0, 0);
        acc1 = __builtin_amdgcn_mfma_f32_16x16x32_bf16(a, bv1, acc1, 0, 0, 0);
      }
      ln_tanh_store<16>(acc0, acc1, g3, be3, hA, wave, lane, lnpart, lnmr);
    }
    // L4 (wave 0 only): hA -> out (14 cols)
    if (wave == 0) {
      float bc = bias4[acol];
      floatx4 acc = {bc, bc, bc, bc};
#pragma unroll
      for (int ks = 0; ks < 4; ks++) {
        short8 a = *reinterpret_cast<const short8*>(&hA[arow][ks * 32 + agrp * 8]);
        short8 bv = *reinterpret_cast<const short8*>(&wf[40960 + (ks * 64 + lane) * 8]);
        acc = __builtin_amdgcn_mfma_f32_16x16x32_bf16(a, bv, acc, 0, 0, 0);
      }
      if (acol < 14) {
#pragma unroll
        for (int r = 0; r < 4; r++) {
          int row = rbase + r;
          out[(size_t)(b0 * 256 + row0 + row) * 14 + acol] = acc[r];
        }
      }
    }
    __syncthreads();
  }
}

extern "C" void kernel_launch(void* const* d_in, const int* in_sizes, int n_in,
                              void* d_out, int out_size, void* d_ws, size_t ws_size,
                              hipStream_t stream) {
  const float* t = (const float*)d_in[0];
  const float* ctx = (const float*)d_in[1];
  const float* ce_w = (const float*)d_in[2];
  const float* ce_b = (const float*)d_in[3];
  const float* z0_w = (const float*)d_in[4];
  const float* z0_b = (const float*)d_in[5];
  const float* dw0 = (const float*)d_in[6];
  const float* db0 = (const float*)d_in[7];
  const float* dw1 = (const float*)d_in[8];
  const float* db1 = (const float*)d_in[9];
  const float* dw2 = (const float*)d_in[10];
  const float* db2 = (const float*)d_in[11];
  const float* dw3 = (const float*)d_in[12];
  const float* db3 = (const float*)d_in[13];
  const float* dg0 = (const float*)d_in[14];
  const float* dbe0 = (const float*)d_in[15];
  const float* dg1 = (const float*)d_in[16];
  const float* dbe1 = (const float*)d_in[17];
  const float* dg2 = (const float*)d_in[18];
  const float* dbe2 = (const float*)d_in[19];
  const float* ew0 = (const float*)d_in[20];
  const float* eb0 = (const float*)d_in[21];
  const float* ew1 = (const float*)d_in[22];
  const float* eb1 = (const float*)d_in[23];
  const float* ew2 = (const float*)d_in[24];
  const float* eb2 = (const float*)d_in[25];
  const float* ew3 = (const float*)d_in[26];
  const float* eb3 = (const float*)d_in[27];
  const float* eg0 = (const float*)d_in[28];
  const float* ebe0 = (const float*)d_in[29];
  const float* eg1 = (const float*)d_in[30];
  const float* ebe1 = (const float*)d_in[31];
  const float* eg2 = (const float*)d_in[32];
  const float* ebe2 = (const float*)d_in[33];
  float* out = (float*)d_out;

  char* ws = (char*)d_ws;
  u16* wdyn = (u16*)(ws + 0);            // 61440 elems = 122880 B
  u16* wdec = (u16*)(ws + 122880);       // 43008 elems =  86016 B
  u16* ctxb = (u16*)(ws + 208896);       // 2048*64 bf16 = 262144 B
  float* ctxf = (float*)(ws + 471040);   // 2048*64 f32  = 524288 B
  float* z0f = (float*)(ws + 995328);    // 2048*64 f32  = 524288 B
  u16* zt = (u16*)(ws + 1519616);        // z_traj bf16, up to 2048*256*64*2 = 67108864 B
  size_t zt_avail = (ws_size > 1519616) ? ws_size - 1519616 : 0;

  // pack dynamics + decoder weights into fragment order
  rlp_pack_frag<<<80, 256, 0, stream>>>(dw0, wdyn + 0, 145, 128, 5, 8);
  rlp_pack_frag<<<64, 256, 0, stream>>>(dw1, wdyn + 20480, 128, 128, 4, 8);
  rlp_pack_frag<<<64, 256, 0, stream>>>(dw2, wdyn + 36864, 128, 128, 4, 8);
  rlp_pack_frag<<<32, 256, 0, stream>>>(dw3, wdyn + 53248, 128, 64, 4, 4);
  rlp_pack_frag<<<32, 256, 0, stream>>>(ew0, wdec + 0, 64, 128, 2, 8);
  rlp_pack_frag<<<64, 256, 0, stream>>>(ew1, wdec + 8192, 128, 128, 4, 8);
  rlp_pack_frag<<<64, 256, 0, stream>>>(ew2, wdec + 24576, 128, 128, 4, 8);
  rlp_pack_frag<<<8, 256, 0, stream>>>(ew3, wdec + 40960, 128, 14, 4, 1);
  rlp_ctx_kernel<<<512, 256, 0, stream>>>(ctx, ce_w, ce_b, ctxb, ctxf);
  rlp_z0_kernel<<<512, 256, 0, stream>>>(ctxf, z0_w, z0_b, z0f);

  // chunk over B if ws is too small for the full bf16 z_traj (32 KiB per batch row)
  const size_t per_row = (size_t)N_ * 64 * 2;
  int chunkB = B_;
  if (zt_avail < (size_t)B_ * per_row) {
    chunkB = (int)(zt_avail / per_row) & ~7;
    if (chunkB < 8) chunkB = 8;
  }
  for (int b0 = 0; b0 < B_; b0 += chunkB) {
    int cb = (B_ - b0 < chunkB) ? (B_ - b0) : chunkB;
    rlp_scan_kernel<<<cb / 8, 256, 0, stream>>>(t, wdyn, ctxb, z0f,
        db0, db1, db2, db3, dg0, dbe0, dg1, dbe1, dg2, dbe2, zt, b0);
    rlp_dec_kernel<<<256, 256, 0, stream>>>(wdec, zt,
        eb0, eb1, eb2, eb3, eg0, ebe0, eg1, ebe1, eg2, ebe2, out, b0, cb * 256);
  }
}

// Round 2
// 984.634 us; speedup vs baseline: 1.6877x; 1.6877x over previous
//
#include <hip/hip_runtime.h>
#include <cstdint>
#include <cstddef>

#define B_ 2048
#define N_ 256

typedef unsigned short u16;
typedef unsigned int u32;
typedef __attribute__((ext_vector_type(8))) short short8;
typedef __attribute__((ext_vector_type(4))) float floatx4;

__device__ __forceinline__ u16 f2bf(float f) {
  union { float f; unsigned u; } v; v.f = f;
  unsigned u = v.u;
  return (u16)((u + 0x7FFFu + ((u >> 16) & 1u)) >> 16);
}
__device__ __forceinline__ u32 pack2bf(float a, float b) {
  return (u32)f2bf(a) | ((u32)f2bf(b) << 16);
}
__device__ __forceinline__ float tanh_fast(float x) {
  x = fmaxf(fminf(x, 30.0f), -30.0f);
  float u = __expf(-2.0f * x);
  return __fdividef(1.0f - u, 1.0f + u);
}

// ---------------- prep: pack W[K][Ncols] (fp32, row-major) into fragment-ordered bf16:
// elem = ((nt*ksteps + ks)*64 + lane)*8 + j ; maps to W[k = ks*32+(lane>>4)*8+j][nt*16+(lane&15)]
// Used as the A-operand (W^T tile: row=wcol=lane&15, k=(lane>>4)*8+j)  -- same blob as before.
__global__ void rlp_pack_frag(const float* __restrict__ W, u16* __restrict__ dst,
                              int K, int Ncols, int ksteps, int ntiles) {
  int e = blockIdx.x * blockDim.x + threadIdx.x;
  int total = ntiles * ksteps * 512;
  if (e >= total) return;
  int j = e & 7;
  int lane = (e >> 3) & 63;
  int tt = e >> 9;
  int ks = tt % ksteps;
  int nt = tt / ksteps;
  int col = nt * 16 + (lane & 15);
  int k = ks * 32 + ((lane >> 4) << 3) + j;
  float v = 0.0f;
  if (k < K && col < Ncols) v = W[k * Ncols + col];
  dst[e] = f2bf(v);
}

__global__ void rlp_ctx_kernel(const float* __restrict__ ctx, const float* __restrict__ cew,
                               const float* __restrict__ ceb,
                               u16* __restrict__ ctxb, float* __restrict__ ctxf) {
  int i = blockIdx.x * blockDim.x + threadIdx.x;
  if (i >= B_ * 64) return;
  int b = i >> 6, c = i & 63;
  float s = ceb[c];
#pragma unroll
  for (int k = 0; k < 32; k++) s += ctx[b * 32 + k] * cew[k * 64 + c];
  float v = tanhf(s);
  ctxf[i] = v;
  ctxb[i] = f2bf(v);
}

__global__ void rlp_z0_kernel(const float* __restrict__ ctxf, const float* __restrict__ z0w,
                              const float* __restrict__ z0b, float* __restrict__ z0f) {
  int i = blockIdx.x * blockDim.x + threadIdx.x;
  if (i >= B_ * 64) return;
  int b = i >> 6, l = i & 63;
  float s = z0b[l];
  for (int c = 0; c < 64; c++) s += ctxf[b * 64 + c] * z0w[c * 64 + l];
  z0f[i] = tanhf(s);
}

// ---------------- one hidden layer: swapped MFMA (A=W^T frag from regs, B=x^T frag from LDS),
// C[wcol][brow]; LN over wcols = 3 in-lane adds + shfl_xor(16,32) + cross-wave via LDS partials,
// single barrier, redundant per-lane finalize; tanh; bf16 pack into dst.
template <int KS, int NROW>
__device__ __forceinline__ void mlp_layer(
    const short8 (&wf)[KS], floatx4 bv, floatx4 gv, floatx4 ev,
    const u16* src, int sstride, u16* dst, int dstride,
    float* lnbuf, int wv, int lane) {
  const int rrow = lane & 15;
  const int g = lane >> 4;
  const int srow = (NROW == 8) ? (rrow & 7) : rrow;
  short8 xf[KS];
#pragma unroll
  for (int ks = 0; ks < KS; ks++)
    xf[ks] = *reinterpret_cast<const short8*>(&src[srow * sstride + ks * 32 + g * 8]);
  floatx4 acc = bv;
#pragma unroll
  for (int ks = 0; ks < KS; ks++)
    acc = __builtin_amdgcn_mfma_f32_16x16x32_bf16(wf[ks], xf[ks], acc, 0, 0, 0);
  float s = acc[0] + acc[1] + acc[2] + acc[3];
  float q = acc[0] * acc[0] + acc[1] * acc[1] + acc[2] * acc[2] + acc[3] * acc[3];
  s += __shfl_xor(s, 16, 64); q += __shfl_xor(q, 16, 64);
  s += __shfl_xor(s, 32, 64); q += __shfl_xor(q, 32, 64);
  if (lane < NROW) {
    *reinterpret_cast<float2*>(&lnbuf[lane * 20 + 2 * wv]) = make_float2(s, q);
  }
  __syncthreads();
  floatx4 p0 = *reinterpret_cast<const floatx4*>(&lnbuf[srow * 20 + 0]);
  floatx4 p1 = *reinterpret_cast<const floatx4*>(&lnbuf[srow * 20 + 4]);
  floatx4 p2 = *reinterpret_cast<const floatx4*>(&lnbuf[srow * 20 + 8]);
  floatx4 p3 = *reinterpret_cast<const floatx4*>(&lnbuf[srow * 20 + 12]);
  float S = p0[0] + p0[2] + p1[0] + p1[2] + p2[0] + p2[2] + p3[0] + p3[2];
  float Q = p0[1] + p0[3] + p1[1] + p1[3] + p2[1] + p2[3] + p3[1] + p3[3];
  float mean = S * (1.0f / 128.0f);
  float rs = rsqrtf(Q * (1.0f / 128.0f) - mean * mean + 1e-5f);
  float h0 = tanh_fast((acc[0] - mean) * rs * gv[0] + ev[0]);
  float h1 = tanh_fast((acc[1] - mean) * rs * gv[1] + ev[1]);
  float h2 = tanh_fast((acc[2] - mean) * rs * gv[2] + ev[2]);
  float h3 = tanh_fast((acc[3] - mean) * rs * gv[3] + ev[3]);
  if (rrow < NROW) {
    int f = 16 * wv + 4 * g;
    *reinterpret_cast<u32*>(&dst[rrow * dstride + f]) = pack2bf(h0, h1);
    *reinterpret_cast<u32*>(&dst[rrow * dstride + f + 2]) = pack2bf(h2, h3);
  }
  __syncthreads();
}

// ---------------- scan: 512 threads (8 waves), 8 batch rows per WG, weights in VGPRs,
// wave w owns col-tile w; z state in registers of waves 0-3; waves 4-7 compute next-step
// Fourier embedding concurrently with L4.
__global__ __launch_bounds__(512, 2) void rlp_scan2(
    const float* __restrict__ t, const u16* __restrict__ wdyn,
    const u16* __restrict__ ctxb, const float* __restrict__ z0f,
    const float* __restrict__ db0, const float* __restrict__ db1,
    const float* __restrict__ db2, const float* __restrict__ db3,
    const float* __restrict__ dg0, const float* __restrict__ dbe0,
    const float* __restrict__ dg1, const float* __restrict__ dbe1,
    const float* __restrict__ dg2, const float* __restrict__ dbe2,
    u16* __restrict__ ztraj, int b0) {
  __shared__ __align__(16) u16 xb[8][168];   // f: 0-63 z | 64-80 temb | 81-144 ctx | 145+ zero
  __shared__ __align__(16) u16 hA[8][136];
  __shared__ __align__(16) u16 hB[8][136];
  __shared__ __align__(16) float lnS[8 * 20];
  __shared__ float dts[2][8];

  const int tid = threadIdx.x;
  const int wv = tid >> 6;
  const int lane = tid & 63;
  const int rrow = lane & 15;
  const int g = lane >> 4;
  const int r8 = rrow & 7;
  const int w4 = wv & 3;
  const int fb = 16 * wv + 4 * g;
  const int fb4 = 16 * w4 + 4 * g;
  const int gb = b0 + blockIdx.x * 8;

  // loop-invariant consts in registers
  const floatx4 b1 = *(const floatx4*)&db0[fb];
  const floatx4 g1 = *(const floatx4*)&dg0[fb];
  const floatx4 e1 = *(const floatx4*)&dbe0[fb];
  const floatx4 b2 = *(const floatx4*)&db1[fb];
  const floatx4 g2 = *(const floatx4*)&dg1[fb];
  const floatx4 e2 = *(const floatx4*)&dbe1[fb];
  const floatx4 b3 = *(const floatx4*)&db2[fb];
  const floatx4 g3 = *(const floatx4*)&dg2[fb];
  const floatx4 e3 = *(const floatx4*)&dbe2[fb];
  const floatx4 b4 = *(const floatx4*)&db3[fb4];

  short8 wf1[5], wf2[4], wf3[4], wf4[4];
#pragma unroll
  for (int ks = 0; ks < 5; ks++)
    wf1[ks] = *(const short8*)(wdyn + ((size_t)(wv * 5 + ks) * 64 + lane) * 8);
#pragma unroll
  for (int ks = 0; ks < 4; ks++)
    wf2[ks] = *(const short8*)(wdyn + 20480 + ((size_t)(wv * 4 + ks) * 64 + lane) * 8);
#pragma unroll
  for (int ks = 0; ks < 4; ks++)
    wf3[ks] = *(const short8*)(wdyn + 36864 + ((size_t)(wv * 4 + ks) * 64 + lane) * 8);
#pragma unroll
  for (int ks = 0; ks < 4; ks++)
    wf4[ks] = *(const short8*)(wdyn + 53248 + ((size_t)(w4 * 4 + ks) * 64 + lane) * 8);

  for (int i = tid; i < 8 * 168; i += 512) (&xb[0][0])[i] = 0;
  __syncthreads();
  // ctx fill (all 512 threads: one u16 each)
  {
    int b = tid >> 6, c = tid & 63;
    xb[b][81 + c] = ctxb[(size_t)(gb + b) * 64 + c];
  }
  // temb(0), dts(0)
  if (tid < 136) {
    int b = tid / 17, j = tid - b * 17;
    float tv = t[(size_t)(gb + b) * N_];
    float val = (j == 0) ? tv
              : (j <= 8 ? __sinf(tv * (3.14159265358979f * (float)(1 << (j - 1))))
                        : __cosf(tv * (3.14159265358979f * (float)(1 << (j - 9)))));
    xb[b][64 + j] = f2bf(val);
  }
  if (tid < 8) dts[0][tid] = t[(size_t)(gb + tid) * N_ + 1] - t[(size_t)(gb + tid) * N_];
  // z0 into regs + xb + ztraj step 0
  float zr0, zr1, zr2, zr3;
  {
    const floatx4 zv = *(const floatx4*)&z0f[(size_t)(gb + r8) * 64 + fb4];
    zr0 = zv[0]; zr1 = zv[1]; zr2 = zv[2]; zr3 = zv[3];
    if (wv < 4 && rrow < 8) {
      u32 lo = pack2bf(zr0, zr1), hi = pack2bf(zr2, zr3);
      *(u32*)&xb[rrow][fb4] = lo;
      *(u32*)&xb[rrow][fb4 + 2] = hi;
      size_t zi = ((size_t)(blockIdx.x * 8 + rrow) * N_) * 64 + fb4;
      *(u32*)&ztraj[zi] = lo;
      *(u32*)&ztraj[zi + 2] = hi;
    }
  }
  __syncthreads();

  for (int n = 0; n < N_ - 1; n++) {
    mlp_layer<5, 8>(wf1, b1, g1, e1, &xb[0][0], 168, &hA[0][0], 136, lnS, wv, lane);
    mlp_layer<4, 8>(wf2, b2, g2, e2, &hA[0][0], 136, &hB[0][0], 136, lnS, wv, lane);
    mlp_layer<4, 8>(wf3, b3, g3, e3, &hB[0][0], 136, &hA[0][0], 136, lnS, wv, lane);
    if (wv < 4) {
      // L4: dz for cols [16*wv .. 16*wv+15]; z update in registers
      short8 xf[4];
#pragma unroll
      for (int ks = 0; ks < 4; ks++)
        xf[ks] = *reinterpret_cast<const short8*>(&hA[r8][ks * 32 + g * 8]);
      floatx4 da = b4;
#pragma unroll
      for (int ks = 0; ks < 4; ks++)
        da = __builtin_amdgcn_mfma_f32_16x16x32_bf16(wf4[ks], xf[ks], da, 0, 0, 0);
      float dt = dts[n & 1][r8];
      zr0 += dt * da[0]; zr1 += dt * da[1]; zr2 += dt * da[2]; zr3 += dt * da[3];
      if (rrow < 8) {
        u32 lo = pack2bf(zr0, zr1), hi = pack2bf(zr2, zr3);
        *(u32*)&xb[rrow][fb4] = lo;
        *(u32*)&xb[rrow][fb4 + 2] = hi;
        size_t zi = ((size_t)(blockIdx.x * 8 + rrow) * N_ + (n + 1)) * 64 + fb4;
        *(u32*)&ztraj[zi] = lo;
        *(u32*)&ztraj[zi + 2] = hi;
      }
    } else {
      // waves 4-7: next-step Fourier embedding + dt, overlapped with L4
      int t2 = tid - 256;
      if (n < N_ - 2) {
        if (t2 < 136) {
          int b = t2 / 17, j = t2 - b * 17;
          float tv = t[(size_t)(gb + b) * N_ + n + 1];
          float val = (j == 0) ? tv
                    : (j <= 8 ? __sinf(tv * (3.14159265358979f * (float)(1 << (j - 1))))
                              : __cosf(tv * (3.14159265358979f * (float)(1 << (j - 9)))));
          xb[b][64 + j] = f2bf(val);
        }
        if (t2 < 8)
          dts[(n + 1) & 1][t2] =
              t[(size_t)(gb + t2) * N_ + n + 2] - t[(size_t)(gb + t2) * N_ + n + 1];
      }
    }
    __syncthreads();
  }
}

// ---------------- decoder: 512 threads (8 waves), weights in VGPRs, 16 rows/iter,
// grid-stride persistent; coalesced output flush staged via LDS.
__global__ __launch_bounds__(512, 4) void rlp_dec2(
    const u16* __restrict__ wdec, const u16* __restrict__ ztraj,
    const float* __restrict__ eb0, const float* __restrict__ eb1,
    const float* __restrict__ eb2, const float* __restrict__ eb3,
    const float* __restrict__ eg0, const float* __restrict__ ebe0,
    const float* __restrict__ eg1, const float* __restrict__ ebe1,
    const float* __restrict__ eg2, const float* __restrict__ ebe2,
    float* __restrict__ out, int b0, int nrows) {
  __shared__ __align__(16) u16 xz[16][72];
  __shared__ __align__(16) u16 hA[16][136];
  __shared__ __align__(16) u16 hB[16][136];
  __shared__ __align__(16) float lnD[16 * 20];
  __shared__ float obuf[224];
  __shared__ float bias1[128], bias2[128], bias3[128], bias4[16];
  __shared__ float g1s[128], e1s[128], g2s[128], e2s[128], g3s[128], e3s[128];

  const int tid = threadIdx.x;
  const int wv = tid >> 6;
  const int lane = tid & 63;
  const int rrow = lane & 15;
  const int g = lane >> 4;
  const int fb = 16 * wv + 4 * g;

  short8 wf1[2], wf2[4], wf3[4], wf4[4];
#pragma unroll
  for (int ks = 0; ks < 2; ks++)
    wf1[ks] = *(const short8*)(wdec + ((size_t)(wv * 2 + ks) * 64 + lane) * 8);
#pragma unroll
  for (int ks = 0; ks < 4; ks++)
    wf2[ks] = *(const short8*)(wdec + 8192 + ((size_t)(wv * 4 + ks) * 64 + lane) * 8);
#pragma unroll
  for (int ks = 0; ks < 4; ks++)
    wf3[ks] = *(const short8*)(wdec + 24576 + ((size_t)(wv * 4 + ks) * 64 + lane) * 8);
#pragma unroll
  for (int ks = 0; ks < 4; ks++)
    wf4[ks] = *(const short8*)(wdec + 40960 + ((size_t)ks * 64 + lane) * 8);

  for (int i = tid; i < 128; i += 512) {
    bias1[i] = eb0[i]; bias2[i] = eb1[i]; bias3[i] = eb2[i];
    g1s[i] = eg0[i]; e1s[i] = ebe0[i];
    g2s[i] = eg1[i]; e2s[i] = ebe1[i];
    g3s[i] = eg2[i]; e3s[i] = ebe2[i];
  }
  if (tid < 16) bias4[tid] = (tid < 14) ? eb3[tid] : 0.0f;
  __syncthreads();

  const floatx4 b1 = *(const floatx4*)&bias1[fb];
  const floatx4 g1v = *(const floatx4*)&g1s[fb];
  const floatx4 e1v = *(const floatx4*)&e1s[fb];
  const floatx4 b2 = *(const floatx4*)&bias2[fb];
  const floatx4 g2v = *(const floatx4*)&g2s[fb];
  const floatx4 e2v = *(const floatx4*)&e2s[fb];
  const floatx4 b3 = *(const floatx4*)&bias3[fb];
  const floatx4 g3v = *(const floatx4*)&g3s[fb];
  const floatx4 e3v = *(const floatx4*)&e3s[fb];
  const floatx4 b4 = *(const floatx4*)&bias4[4 * g];

  const int ntiles = nrows >> 4;
  int prevbase = -1;
  for (int tile = blockIdx.x; tile < ntiles; tile += gridDim.x) {
    if (prevbase >= 0 && tid < 224) out[prevbase + tid] = obuf[tid];
    if (tid < 128) {
      int rr = tid >> 3, p = tid & 7;
      *reinterpret_cast<short8*>(&xz[rr][p * 8]) =
          *reinterpret_cast<const short8*>(&ztraj[(size_t)(tile * 16 + rr) * 64 + p * 8]);
    }
    __syncthreads();
    mlp_layer<2, 16>(wf1, b1, g1v, e1v, &xz[0][0], 72, &hA[0][0], 136, lnD, wv, lane);
    mlp_layer<4, 16>(wf2, b2, g2v, e2v, &hA[0][0], 136, &hB[0][0], 136, lnD, wv, lane);
    mlp_layer<4, 16>(wf3, b3, g3v, e3v, &hB[0][0], 136, &hA[0][0], 136, lnD, wv, lane);
    if (wv == 0) {
      short8 xf[4];
#pragma unroll
      for (int ks = 0; ks < 4; ks++)
        xf[ks] = *reinterpret_cast<const short8*>(&hA[rrow][ks * 32 + g * 8]);
      floatx4 da = b4;
#pragma unroll
      for (int ks = 0; ks < 4; ks++)
        da = __builtin_amdgcn_mfma_f32_16x16x32_bf16(wf4[ks], xf[ks], da, 0, 0, 0);
#pragma unroll
      for (int r = 0; r < 4; r++) {
        int wc = 4 * g + r;
        if (wc < 14) obuf[rrow * 14 + wc] = da[r];
      }
    }
    __syncthreads();
    prevbase = b0 * 3584 + tile * 224;
  }
  if (prevbase >= 0 && tid < 224) out[prevbase + tid] = obuf[tid];
}

extern "C" void kernel_launch(void* const* d_in, const int* in_sizes, int n_in,
                              void* d_out, int out_size, void* d_ws, size_t ws_size,
                              hipStream_t stream) {
  const float* t = (const float*)d_in[0];
  const float* ctx = (const float*)d_in[1];
  const float* ce_w = (const float*)d_in[2];
  const float* ce_b = (const float*)d_in[3];
  const float* z0_w = (const float*)d_in[4];
  const float* z0_b = (const float*)d_in[5];
  const float* dw0 = (const float*)d_in[6];
  const float* db0 = (const float*)d_in[7];
  const float* dw1 = (const float*)d_in[8];
  const float* db1 = (const float*)d_in[9];
  const float* dw2 = (const float*)d_in[10];
  const float* db2 = (const float*)d_in[11];
  const float* dw3 = (const float*)d_in[12];
  const float* db3 = (const float*)d_in[13];
  const float* dg0 = (const float*)d_in[14];
  const float* dbe0 = (const float*)d_in[15];
  const float* dg1 = (const float*)d_in[16];
  const float* dbe1 = (const float*)d_in[17];
  const float* dg2 = (const float*)d_in[18];
  const float* dbe2 = (const float*)d_in[19];
  const float* ew0 = (const float*)d_in[20];
  const float* eb0 = (const float*)d_in[21];
  const float* ew1 = (const float*)d_in[22];
  const float* eb1 = (const float*)d_in[23];
  const float* ew2 = (const float*)d_in[24];
  const float* eb2 = (const float*)d_in[25];
  const float* ew3 = (const float*)d_in[26];
  const float* eb3 = (const float*)d_in[27];
  const float* eg0 = (const float*)d_in[28];
  const float* ebe0 = (const float*)d_in[29];
  const float* eg1 = (const float*)d_in[30];
  const float* ebe1 = (const float*)d_in[31];
  const float* eg2 = (const float*)d_in[32];
  const float* ebe2 = (const float*)d_in[33];
  float* out = (float*)d_out;

  char* ws = (char*)d_ws;
  u16* wdyn = (u16*)(ws + 0);            // 61440 elems = 122880 B
  u16* wdec = (u16*)(ws + 122880);       // 43008 elems =  86016 B
  u16* ctxb = (u16*)(ws + 208896);       // 2048*64 bf16
  float* ctxf = (float*)(ws + 471040);   // 2048*64 f32
  float* z0f = (float*)(ws + 995328);    // 2048*64 f32
  u16* zt = (u16*)(ws + 1519616);        // z_traj bf16
  size_t zt_avail = (ws_size > 1519616) ? ws_size - 1519616 : 0;

  rlp_pack_frag<<<80, 256, 0, stream>>>(dw0, wdyn + 0, 145, 128, 5, 8);
  rlp_pack_frag<<<64, 256, 0, stream>>>(dw1, wdyn + 20480, 128, 128, 4, 8);
  rlp_pack_frag<<<64, 256, 0, stream>>>(dw2, wdyn + 36864, 128, 128, 4, 8);
  rlp_pack_frag<<<32, 256, 0, stream>>>(dw3, wdyn + 53248, 128, 64, 4, 4);
  rlp_pack_frag<<<32, 256, 0, stream>>>(ew0, wdec + 0, 64, 128, 2, 8);
  rlp_pack_frag<<<64, 256, 0, stream>>>(ew1, wdec + 8192, 128, 128, 4, 8);
  rlp_pack_frag<<<64, 256, 0, stream>>>(ew2, wdec + 24576, 128, 128, 4, 8);
  rlp_pack_frag<<<8, 256, 0, stream>>>(ew3, wdec + 40960, 128, 14, 4, 1);
  rlp_ctx_kernel<<<512, 256, 0, stream>>>(ctx, ce_w, ce_b, ctxb, ctxf);
  rlp_z0_kernel<<<512, 256, 0, stream>>>(ctxf, z0_w, z0_b, z0f);

  const size_t per_row = (size_t)N_ * 64 * 2;
  int chunkB = B_;
  if (zt_avail < (size_t)B_ * per_row) {
    chunkB = (int)(zt_avail / per_row) & ~7;
    if (chunkB < 8) chunkB = 8;
  }
  for (int b0 = 0; b0 < B_; b0 += chunkB) {
    int cb = (B_ - b0 < chunkB) ? (B_ - b0) : chunkB;
    rlp_scan2<<<cb / 8, 512, 0, stream>>>(t, wdyn, ctxb, z0f,
        db0, db1, db2, db3, dg0, dbe0, dg1, dbe1, dg2, dbe2, zt, b0);
    int ntiles = cb * 16;
    int ngrid = ntiles < 1024 ? ntiles : 1024;
    rlp_dec2<<<ngrid, 512, 0, stream>>>(wdec, zt,
        eb0, eb1, eb2, eb3, eg0, ebe0, eg1, ebe1, eg2, ebe2, out, b0, cb * 256);
  }
}